// Round 1
// baseline (511.858 us; speedup 1.0000x reference)
//
#include <hip/hip_runtime.h>
#include <hip/hip_bf16.h>
#include <stdint.h>

#define DM   2048
#define SEQ  2048
#define NB   2
#define NH   16
#define DK   128
#define MTOT (NB * SEQ) // 4096

typedef __bf16 bf16;
typedef __bf16 bf16x8 __attribute__((ext_vector_type(8)));
typedef __bf16 bf16x4v __attribute__((ext_vector_type(4)));
typedef float f32x4 __attribute__((ext_vector_type(4)));

__device__ __forceinline__ void gload_lds16(const void* g, void* l) {
  __builtin_amdgcn_global_load_lds((__attribute__((address_space(1))) void*)(g),
                                   (__attribute__((address_space(3))) void*)(l),
                                   16, 0, 0);
}

__device__ __forceinline__ f32x4 mfma16(bf16x8 a, bf16x8 b, f32x4 c) {
  return __builtin_amdgcn_mfma_f32_16x16x32_bf16(a, b, c, 0, 0, 0);
}

// ---------------- fp32 -> bf16 cast (vectorized) ----------------
__global__ void cast_kernel(const float* __restrict__ in, bf16* __restrict__ out, int n4) {
  int i = blockIdx.x * blockDim.x + threadIdx.x;
  if (i < n4) {
    float4 v = reinterpret_cast<const float4*>(in)[i];
    bf16x4v o;
    o[0] = (bf16)v.x; o[1] = (bf16)v.y; o[2] = (bf16)v.z; o[3] = (bf16)v.w;
    *reinterpret_cast<bf16x4v*>(out + (size_t)i * 4) = o;
  }
}

// ---------------- GEMM: C[M,N] = A[M,K] * W[N,K]^T + bias ----------------
// MODE 0: bf16 out, layout [B,H,S,DK]   (q, k)
// MODE 1: bf16 out, layout [B,H,DK,S]   (v transposed)
// MODE 2: f32 out, layout [M, N]        (final projection)
template <int MODE>
__global__ __launch_bounds__(256, 2) void gemm_bt(
    const bf16* __restrict__ A, const bf16* __restrict__ W,
    const float* __restrict__ bias, void* __restrict__ out) {
  __shared__ bf16 lA[128 * 64];
  __shared__ bf16 lB[128 * 64];

  const int tid = threadIdx.x;
  const int lane = tid & 63;
  const int wid = tid >> 6;
  const int wr = wid >> 1, wc = wid & 1;
  const int row0 = blockIdx.y * 128;
  const int col0 = blockIdx.x * 128;

  // staging constants: 8-row chunks of 128B rows, XOR-swizzled source col
  const int srow = lane >> 3;                 // row within chunk
  const int scol = ((lane & 7) ^ srow) * 8;   // source col elements (pre-swizzled)

  const int fr = lane & 15;   // fragment row
  const int fg = lane >> 4;   // k-group

  f32x4 acc[4][4];
#pragma unroll
  for (int m = 0; m < 4; ++m)
#pragma unroll
    for (int n = 0; n < 4; ++n) { f32x4 z = {0.f, 0.f, 0.f, 0.f}; acc[m][n] = z; }

  for (int kt = 0; kt < DM / 64; ++kt) {
    const int k0 = kt * 64;
    __syncthreads();
#pragma unroll
    for (int i = 0; i < 4; ++i) {
      const int chunk = wid * 4 + i;
      const int r = chunk * 8 + srow;
      gload_lds16(A + (size_t)(row0 + r) * DM + k0 + scol, lA + chunk * 512);
      gload_lds16(W + (size_t)(col0 + r) * DM + k0 + scol, lB + chunk * 512);
    }
    __syncthreads();
#pragma unroll
    for (int kk = 0; kk < 2; ++kk) {
      bf16x8 af[4], bw[4];
#pragma unroll
      for (int m = 0; m < 4; ++m) {
        const int r = wr * 64 + m * 16 + fr;
        const int cb = (kk * 64 + fg * 16) ^ ((r & 7) << 4);
        af[m] = *(const bf16x8*)((const char*)lA + r * 128 + cb);
      }
#pragma unroll
      for (int n = 0; n < 4; ++n) {
        const int r = wc * 64 + n * 16 + fr;
        const int cb = (kk * 64 + fg * 16) ^ ((r & 7) << 4);
        bw[n] = *(const bf16x8*)((const char*)lB + r * 128 + cb);
      }
#pragma unroll
      for (int m = 0; m < 4; ++m)
#pragma unroll
        for (int n = 0; n < 4; ++n) acc[m][n] = mfma16(af[m], bw[n], acc[m][n]);
    }
  }

  // epilogue: C row = (lane>>4)*4 + reg, col = lane&15 (m89-verified)
#pragma unroll
  for (int m = 0; m < 4; ++m) {
#pragma unroll
    for (int n = 0; n < 4; ++n) {
      const int col = col0 + wc * 64 + n * 16 + fr;
      const float bs = bias[col];
      const int rbase = row0 + wr * 64 + m * 16 + fg * 4;
      if (MODE == 0) {
        bf16* o = (bf16*)out;
        const int h = col >> 7, d = col & 127;
#pragma unroll
        for (int r = 0; r < 4; ++r) {
          const int row = rbase + r;
          const int b = row >> 11, s = row & 2047;
          o[(((size_t)(b * NH + h) * SEQ + s) << 7) + d] = (bf16)(acc[m][n][r] + bs);
        }
      } else if (MODE == 1) {
        bf16* o = (bf16*)out;
        const int h = col >> 7, d = col & 127;
        const int b = rbase >> 11, s = rbase & 2047;
        bf16x4v pk;
#pragma unroll
        for (int r = 0; r < 4; ++r) pk[r] = (bf16)(acc[m][n][r] + bs);
        *reinterpret_cast<bf16x4v*>(o + ((size_t)((b * NH + h) * DK + d) * SEQ + s)) = pk;
      } else {
        float* o = (float*)out;
#pragma unroll
        for (int r = 0; r < 4; ++r) {
          const int row = rbase + r;
          o[(size_t)row * DM + col] = acc[m][n][r] + bs;
        }
      }
    }
  }
}

// ---------------- flash attention with additive bias ----------------
// grid: (S/128, NH, NB), block 256 (4 waves x 32 q-rows)
__global__ __launch_bounds__(256, 2) void attn_kernel(
    const bf16* __restrict__ Q,   // [B,H,S,DK]
    const bf16* __restrict__ K,   // [B,H,S,DK]
    const bf16* __restrict__ Vt,  // [B,H,DK,S]
    const float* __restrict__ mask,   // [B,S,S]
    const float* __restrict__ hscale, // [NH]
    bf16* __restrict__ O) {           // [B,S,H,DK]
  __shared__ bf16 Kl[64 * 128];
  __shared__ bf16 Vl[128 * 64];
  __shared__ bf16 Pl[128 * 64];

  const int tid = threadIdx.x;
  const int lane = tid & 63;
  const int wid = tid >> 6;
  const int q0 = blockIdx.x * 128;
  const int h = blockIdx.y;
  const int b = blockIdx.z;
  const float hs = hscale[h];
  const float ksc = 0.08838834764831845f; // 1/sqrt(128)

  const size_t bh = (size_t)(b * NH + h);
  const bf16* Qb = Q + bh * SEQ * DK;
  const bf16* Kb = K + bh * SEQ * DK;
  const bf16* Vb = Vt + bh * (size_t)DK * SEQ;

  const int fr = lane & 15, fg = lane >> 4;

  // Q fragments held in registers for this wave's 32 rows
  bf16x8 aq[2][4];
#pragma unroll
  for (int m = 0; m < 2; ++m) {
    const int qr = q0 + wid * 32 + m * 16 + fr;
#pragma unroll
    for (int kk = 0; kk < 4; ++kk)
      aq[m][kk] = *(const bf16x8*)(Qb + (size_t)qr * DK + kk * 32 + fg * 8);
  }

  f32x4 acco[2][8];
#pragma unroll
  for (int m = 0; m < 2; ++m)
#pragma unroll
    for (int nd = 0; nd < 8; ++nd) { f32x4 z = {0.f, 0.f, 0.f, 0.f}; acco[m][nd] = z; }
  float mrun[2][4], lrun[2][4];
#pragma unroll
  for (int m = 0; m < 2; ++m)
#pragma unroll
    for (int r = 0; r < 4; ++r) { mrun[m][r] = -3.0e38f; lrun[m][r] = 0.f; }

  const int k_r = lane >> 4;                 // K tile: 4-row chunks (256B rows)
  const int v_r = lane >> 3;                 // Vt tile: 8-row chunks (128B rows)
  const int v_c = ((lane & 7) ^ v_r) * 8;

  for (int kt = 0; kt < SEQ / 64; ++kt) {
    const int kb0 = kt * 64;
    __syncthreads();
#pragma unroll
    for (int i = 0; i < 4; ++i) {
      const int chunk = wid * 4 + i;
      {
        const int r = chunk * 4 + k_r;
        const int c = ((lane & 15) ^ (r & 7)) * 8;
        gload_lds16(Kb + (size_t)(kb0 + r) * DK + c, Kl + chunk * 512);
      }
      {
        const int r = chunk * 8 + v_r;
        gload_lds16(Vb + (size_t)r * SEQ + kb0 + v_c, Vl + chunk * 512);
      }
    }
    __syncthreads();

    // scores: S = Q K^T
    f32x4 accs[2][4];
#pragma unroll
    for (int m = 0; m < 2; ++m)
#pragma unroll
      for (int n = 0; n < 4; ++n) { f32x4 z = {0.f, 0.f, 0.f, 0.f}; accs[m][n] = z; }
#pragma unroll
    for (int kk = 0; kk < 4; ++kk) {
      bf16x8 bk[4];
#pragma unroll
      for (int n = 0; n < 4; ++n) {
        const int r = n * 16 + fr;
        const int cb = (kk * 64 + fg * 16) ^ ((r & 7) << 4);
        bk[n] = *(const bf16x8*)((const char*)Kl + r * 256 + cb);
      }
#pragma unroll
      for (int m = 0; m < 2; ++m)
#pragma unroll
        for (int n = 0; n < 4; ++n) accs[m][n] = mfma16(aq[m][kk], bk[n], accs[m][n]);
    }

    // bias + online softmax
#pragma unroll
    for (int m = 0; m < 2; ++m) {
      float rmax[4] = {-3.0e38f, -3.0e38f, -3.0e38f, -3.0e38f};
#pragma unroll
      for (int n = 0; n < 4; ++n) {
        const int kcol = kb0 + n * 16 + fr;
        const float* mcol = mask + (size_t)b * SEQ * SEQ + kcol;
#pragma unroll
        for (int r = 0; r < 4; ++r) {
          const int qrow = q0 + wid * 32 + m * 16 + fg * 4 + r;
          float v = accs[m][n][r] * ksc + mcol[(size_t)qrow * SEQ] * hs;
          accs[m][n][r] = v;
          rmax[r] = fmaxf(rmax[r], v);
        }
      }
#pragma unroll
      for (int r = 0; r < 4; ++r) {
        float v = rmax[r];
        v = fmaxf(v, __shfl_xor(v, 1));
        v = fmaxf(v, __shfl_xor(v, 2));
        v = fmaxf(v, __shfl_xor(v, 4));
        v = fmaxf(v, __shfl_xor(v, 8));
        const float mnew = fmaxf(mrun[m][r], v);
        const float sc = __expf(mrun[m][r] - mnew);
        mrun[m][r] = mnew;
#pragma unroll
        for (int nd = 0; nd < 8; ++nd) acco[m][nd][r] *= sc;
        float rs = 0.f;
#pragma unroll
        for (int n = 0; n < 4; ++n) {
          float p = __expf(accs[m][n][r] - mnew);
          accs[m][n][r] = p;
          rs += p;
        }
        rs += __shfl_xor(rs, 1);
        rs += __shfl_xor(rs, 2);
        rs += __shfl_xor(rs, 4);
        rs += __shfl_xor(rs, 8);
        lrun[m][r] = lrun[m][r] * sc + rs;
        // write P row slice to LDS (swizzled)
        const int ql = wid * 32 + m * 16 + fg * 4 + r;
#pragma unroll
        for (int n = 0; n < 4; ++n) {
          const int cbyte = (n * 16 + fr) * 2;
          *(bf16*)((char*)Pl + ql * 128 + (cbyte ^ ((ql & 7) << 4))) = (bf16)accs[m][n][r];
        }
      }
    }

    // O += P V  (A-frag from Pl, B-frag from Vl)
#pragma unroll
    for (int kk = 0; kk < 2; ++kk) {
      bf16x8 pa[2];
#pragma unroll
      for (int m = 0; m < 2; ++m) {
        const int r = wid * 32 + m * 16 + fr;
        const int cb = (kk * 64 + fg * 16) ^ ((r & 7) << 4);
        pa[m] = *(const bf16x8*)((const char*)Pl + r * 128 + cb);
      }
#pragma unroll
      for (int nd = 0; nd < 8; ++nd) {
        const int r = nd * 16 + fr;
        const int cb = (kk * 64 + fg * 16) ^ ((r & 7) << 4);
        bf16x8 bv = *(const bf16x8*)((const char*)Vl + r * 128 + cb);
#pragma unroll
        for (int m = 0; m < 2; ++m) acco[m][nd] = mfma16(pa[m], bv, acco[m][nd]);
      }
    }
  }

  // epilogue: normalize and store O in [B,S,H,DK]
#pragma unroll
  for (int m = 0; m < 2; ++m) {
#pragma unroll
    for (int r = 0; r < 4; ++r) {
      const float inv = 1.f / lrun[m][r];
      const int qrow = q0 + wid * 32 + m * 16 + fg * 4 + r;
      bf16* orow = O + (((size_t)(b * SEQ + qrow) * NH + h) << 7);
#pragma unroll
      for (int nd = 0; nd < 8; ++nd) orow[nd * 16 + fr] = (bf16)(acco[m][nd][r] * inv);
    }
  }
}

extern "C" void kernel_launch(void* const* d_in, const int* in_sizes, int n_in,
                              void* d_out, int out_size, void* d_ws, size_t ws_size,
                              hipStream_t stream) {
  const float* states = (const float*)d_in[0];
  const float* maskp  = (const float*)d_in[1];
  const float* hscale = (const float*)d_in[2];
  const float* qw = (const float*)d_in[3];
  const float* qb = (const float*)d_in[4];
  const float* kw = (const float*)d_in[5];
  const float* kb = (const float*)d_in[6];
  const float* vw = (const float*)d_in[7];
  const float* vb = (const float*)d_in[8];
  const float* ow = (const float*)d_in[9];
  const float* ob = (const float*)d_in[10];

  char* ws = (char*)d_ws;
  const size_t SZ_ACT = (size_t)MTOT * DM * 2;  // 16 MiB
  const size_t SZ_W   = (size_t)DM * DM * 2;    // 8 MiB
  bf16* sb    = (bf16*)(ws);                  // states bf16; later reused as O buffer
  bf16* qbuf  = (bf16*)(ws + SZ_ACT);
  bf16* kbuf  = (bf16*)(ws + 2 * SZ_ACT);
  bf16* vtbuf = (bf16*)(ws + 3 * SZ_ACT);
  bf16* wqb   = (bf16*)(ws + 4 * SZ_ACT);
  bf16* wkb   = (bf16*)(ws + 4 * SZ_ACT + SZ_W);
  bf16* wvb   = (bf16*)(ws + 4 * SZ_ACT + 2 * SZ_W);
  bf16* wob   = (bf16*)(ws + 4 * SZ_ACT + 3 * SZ_W);

  const int nAct4 = MTOT * DM / 4;   // 2097152
  const int nW4   = DM * DM / 4;     // 1048576
  cast_kernel<<<(nAct4 + 255) / 256, 256, 0, stream>>>(states, sb, nAct4);
  cast_kernel<<<(nW4 + 255) / 256, 256, 0, stream>>>(qw, wqb, nW4);
  cast_kernel<<<(nW4 + 255) / 256, 256, 0, stream>>>(kw, wkb, nW4);
  cast_kernel<<<(nW4 + 255) / 256, 256, 0, stream>>>(vw, wvb, nW4);
  cast_kernel<<<(nW4 + 255) / 256, 256, 0, stream>>>(ow, wob, nW4);

  dim3 blk(256);
  dim3 gg(DM / 128, MTOT / 128, 1);
  gemm_bt<0><<<gg, blk, 0, stream>>>(sb, wqb, qb, qbuf);
  gemm_bt<0><<<gg, blk, 0, stream>>>(sb, wkb, kb, kbuf);
  gemm_bt<1><<<gg, blk, 0, stream>>>(sb, wvb, vb, vtbuf);

  dim3 ga(SEQ / 128, NH, NB);
  attn_kernel<<<ga, blk, 0, stream>>>(qbuf, kbuf, vtbuf, maskp, hscale, sb);

  gemm_bt<2><<<gg, blk, 0, stream>>>(sb, wob, ob, d_out);
}

// Round 3
// 368.831 us; speedup vs baseline: 1.3878x; 1.3878x over previous
//
#include <hip/hip_runtime.h>
#include <hip/hip_bf16.h>
#include <stdint.h>

#define DM   2048
#define SEQ  2048
#define NB   2
#define NH   16
#define DK   128
#define MTOT (NB * SEQ) // 4096

typedef __bf16 bf16;
typedef _Float16 f16;
typedef __bf16 bf16x8 __attribute__((ext_vector_type(8)));
typedef __bf16 bf16x4v __attribute__((ext_vector_type(4)));
typedef _Float16 f16x4 __attribute__((ext_vector_type(4)));
typedef float f32x4 __attribute__((ext_vector_type(4)));

__device__ __forceinline__ void gload_lds16(const void* g, void* l) {
  __builtin_amdgcn_global_load_lds((__attribute__((address_space(1))) void*)(g),
                                   (__attribute__((address_space(3))) void*)(l),
                                   16, 0, 0);
}

__device__ __forceinline__ f32x4 mfma16(bf16x8 a, bf16x8 b, f32x4 c) {
  return __builtin_amdgcn_mfma_f32_16x16x32_bf16(a, b, c, 0, 0, 0);
}

// ---------------- fp32 -> bf16 cast (vectorized) ----------------
__global__ void cast_kernel(const float* __restrict__ in, bf16* __restrict__ out, int n4) {
  int i = blockIdx.x * blockDim.x + threadIdx.x;
  if (i < n4) {
    float4 v = reinterpret_cast<const float4*>(in)[i];
    bf16x4v o;
    o[0] = (bf16)v.x; o[1] = (bf16)v.y; o[2] = (bf16)v.z; o[3] = (bf16)v.w;
    *reinterpret_cast<bf16x4v*>(out + (size_t)i * 4) = o;
  }
}

// ---------------- fp32 -> fp16 cast (for bias mask) ----------------
__global__ void cast_half_kernel(const float* __restrict__ in, f16* __restrict__ out, int n4) {
  int i = blockIdx.x * blockDim.x + threadIdx.x;
  if (i < n4) {
    float4 v = reinterpret_cast<const float4*>(in)[i];
    f16x4 o;
    o[0] = (f16)v.x; o[1] = (f16)v.y; o[2] = (f16)v.z; o[3] = (f16)v.w;
    *reinterpret_cast<f16x4*>(out + (size_t)i * 4) = o;
  }
}

// ---------------- GEMM: C[M,N] = A[M,K] * W[N,K]^T + bias ----------------
// MODE 0: bf16 out, layout [B,H,S,DK]   (q, k)
// MODE 1: bf16 out, layout [B,H,DK,S]   (v transposed)
// MODE 2: f32 out, layout [M, N]        (final projection)
template <int MODE>
__global__ __launch_bounds__(256, 2) void gemm_bt(
    const bf16* __restrict__ A, const bf16* __restrict__ W,
    const float* __restrict__ bias, void* __restrict__ out) {
  __shared__ bf16 lA[128 * 64];
  __shared__ bf16 lB[128 * 64];

  const int tid = threadIdx.x;
  const int lane = tid & 63;
  const int wid = tid >> 6;
  const int wr = wid >> 1, wc = wid & 1;
  const int row0 = blockIdx.y * 128;
  const int col0 = blockIdx.x * 128;

  const int srow = lane >> 3;                 // row within chunk
  const int scol = ((lane & 7) ^ srow) * 8;   // pre-swizzled source col

  const int fr = lane & 15;   // fragment row
  const int fg = lane >> 4;   // k-group

  f32x4 acc[4][4];
#pragma unroll
  for (int m = 0; m < 4; ++m)
#pragma unroll
    for (int n = 0; n < 4; ++n) { f32x4 z = {0.f, 0.f, 0.f, 0.f}; acc[m][n] = z; }

  for (int kt = 0; kt < DM / 64; ++kt) {
    const int k0 = kt * 64;
    __syncthreads();
#pragma unroll
    for (int i = 0; i < 4; ++i) {
      const int chunk = wid * 4 + i;
      const int r = chunk * 8 + srow;
      gload_lds16(A + (size_t)(row0 + r) * DM + k0 + scol, lA + chunk * 512);
      gload_lds16(W + (size_t)(col0 + r) * DM + k0 + scol, lB + chunk * 512);
    }
    __syncthreads();
#pragma unroll
    for (int kk = 0; kk < 2; ++kk) {
      bf16x8 af[4], bw[4];
#pragma unroll
      for (int m = 0; m < 4; ++m) {
        const int r = wr * 64 + m * 16 + fr;
        const int cb = (kk * 64 + fg * 16) ^ ((r & 7) << 4);
        af[m] = *(const bf16x8*)((const char*)lA + r * 128 + cb);
      }
#pragma unroll
      for (int n = 0; n < 4; ++n) {
        const int r = wc * 64 + n * 16 + fr;
        const int cb = (kk * 64 + fg * 16) ^ ((r & 7) << 4);
        bw[n] = *(const bf16x8*)((const char*)lB + r * 128 + cb);
      }
#pragma unroll
      for (int m = 0; m < 4; ++m)
#pragma unroll
        for (int n = 0; n < 4; ++n) acc[m][n] = mfma16(af[m], bw[n], acc[m][n]);
    }
  }

#pragma unroll
  for (int m = 0; m < 4; ++m) {
#pragma unroll
    for (int n = 0; n < 4; ++n) {
      const int col = col0 + wc * 64 + n * 16 + fr;
      const float bs = bias[col];
      const int rbase = row0 + wr * 64 + m * 16 + fg * 4;
      if (MODE == 0) {
        bf16* o = (bf16*)out;
        const int h = col >> 7, d = col & 127;
#pragma unroll
        for (int r = 0; r < 4; ++r) {
          const int row = rbase + r;
          const int b = row >> 11, s = row & 2047;
          o[(((size_t)(b * NH + h) * SEQ + s) << 7) + d] = (bf16)(acc[m][n][r] + bs);
        }
      } else if (MODE == 1) {
        bf16* o = (bf16*)out;
        const int h = col >> 7, d = col & 127;
        const int b = rbase >> 11, s = rbase & 2047;
        bf16x4v pk;
#pragma unroll
        for (int r = 0; r < 4; ++r) pk[r] = (bf16)(acc[m][n][r] + bs);
        *reinterpret_cast<bf16x4v*>(o + ((size_t)((b * NH + h) * DK + d) * SEQ + s)) = pk;
      } else {
        float* o = (float*)out;
#pragma unroll
        for (int r = 0; r < 4; ++r) {
          const int row = rbase + r;
          o[(size_t)row * DM + col] = acc[m][n][r] + bs;
        }
      }
    }
  }
}

// ---------------- flash attention with additive bias (mask via LDS) ----------------
// grid: (S/128, NH, NB), block 256 (4 waves x 32 q-rows)
__global__ __launch_bounds__(256, 2) void attn_kernel(
    const bf16* __restrict__ Q,   // [B,H,S,DK]
    const bf16* __restrict__ K,   // [B,H,S,DK]
    const bf16* __restrict__ Vt,  // [B,H,DK,S]
    const f16* __restrict__ maskh,    // [B,S,S] fp16
    const float* __restrict__ hscale, // [NH]
    bf16* __restrict__ O) {           // [B,S,H,DK]
  __shared__ bf16 Kl[64 * 128];
  __shared__ bf16 Vl[128 * 64];
  __shared__ bf16 Pl[128 * 64];
  __shared__ f16  Ml[128 * 64];   // mask tile [128 q][64 k], swizzled

  const int tid = threadIdx.x;
  const int lane = tid & 63;
  const int wid = tid >> 6;
  const int q0 = blockIdx.x * 128;
  const int h = blockIdx.y;
  const int b = blockIdx.z;
  const float hs = hscale[h];
  const float ksc = 0.08838834764831845f; // 1/sqrt(128)

  const size_t bh = (size_t)(b * NH + h);
  const bf16* Qb = Q + bh * SEQ * DK;
  const bf16* Kb = K + bh * SEQ * DK;
  const bf16* Vb = Vt + bh * (size_t)DK * SEQ;
  const f16*  Mb = maskh + (size_t)b * SEQ * SEQ;

  const int fr = lane & 15, fg = lane >> 4;

  // Q fragments in registers
  bf16x8 aq[2][4];
#pragma unroll
  for (int m = 0; m < 2; ++m) {
    const int qr = q0 + wid * 32 + m * 16 + fr;
#pragma unroll
    for (int kk = 0; kk < 4; ++kk)
      aq[m][kk] = *(const bf16x8*)(Qb + (size_t)qr * DK + kk * 32 + fg * 8);
  }

  f32x4 acco[2][8];
#pragma unroll
  for (int m = 0; m < 2; ++m)
#pragma unroll
    for (int nd = 0; nd < 8; ++nd) { f32x4 z = {0.f, 0.f, 0.f, 0.f}; acco[m][nd] = z; }
  float mrun[2][4], lrun[2][4];
#pragma unroll
  for (int m = 0; m < 2; ++m)
#pragma unroll
    for (int r = 0; r < 4; ++r) { mrun[m][r] = -3.0e38f; lrun[m][r] = 0.f; }

  const int k_r = lane >> 4;                 // K tile: 4-row chunks
  const int v_r = lane >> 3;                 // V/M tiles: 8-row chunks
  const int v_c = ((lane & 7) ^ v_r) * 8;
  const int m_c = ((lane & 7) * 8) ^ (((v_r >> 2) & 1) << 4); // pre-swizzled mask col (elems)

  for (int kt = 0; kt < SEQ / 64; ++kt) {
    const int kb0 = kt * 64;
    __syncthreads();
#pragma unroll
    for (int i = 0; i < 4; ++i) {
      const int chunk = wid * 4 + i;
      {
        const int r = chunk * 4 + k_r;
        const int c = ((lane & 15) ^ (r & 7)) * 8;
        gload_lds16(Kb + (size_t)(kb0 + r) * DK + c, Kl + chunk * 512);
      }
      {
        const int r = chunk * 8 + v_r;
        gload_lds16(Vb + (size_t)r * SEQ + kb0 + v_c, Vl + chunk * 512);
      }
      {
        const int r = chunk * 8 + v_r;
        gload_lds16(Mb + (size_t)(q0 + r) * SEQ + kb0 + m_c, Ml + chunk * 512);
      }
    }
    __syncthreads();

    // scores: S = Q K^T
    f32x4 accs[2][4];
#pragma unroll
    for (int m = 0; m < 2; ++m)
#pragma unroll
      for (int n = 0; n < 4; ++n) { f32x4 z = {0.f, 0.f, 0.f, 0.f}; accs[m][n] = z; }
#pragma unroll
    for (int kk = 0; kk < 4; ++kk) {
      bf16x8 bk[4];
#pragma unroll
      for (int n = 0; n < 4; ++n) {
        const int r = n * 16 + fr;
        const int cb = (kk * 64 + fg * 16) ^ ((r & 7) << 4);
        bk[n] = *(const bf16x8*)((const char*)Kl + r * 256 + cb);
      }
#pragma unroll
      for (int m = 0; m < 2; ++m)
#pragma unroll
        for (int n = 0; n < 4; ++n) accs[m][n] = mfma16(aq[m][kk], bk[n], accs[m][n]);
    }

    // bias + online softmax (mask from LDS)
#pragma unroll
    for (int m = 0; m < 2; ++m) {
      float mv[4][4];
#pragma unroll
      for (int n = 0; n < 4; ++n)
#pragma unroll
        for (int r = 0; r < 4; ++r) {
          const int ql = wid * 32 + m * 16 + fg * 4 + r;
          // row-bit2 of ql is (fg&1); swizzle matches staging involution
          mv[n][r] = (float)*(const f16*)((const char*)Ml + ql * 128 + ((n * 32 + fr * 2) ^ ((fg & 1) << 5)));
        }
      float rmax[4] = {-3.0e38f, -3.0e38f, -3.0e38f, -3.0e38f};
#pragma unroll
      for (int n = 0; n < 4; ++n) {
#pragma unroll
        for (int r = 0; r < 4; ++r) {
          float v = accs[m][n][r] * ksc + mv[n][r] * hs;
          accs[m][n][r] = v;
          rmax[r] = fmaxf(rmax[r], v);
        }
      }
#pragma unroll
      for (int r = 0; r < 4; ++r) {
        float v = rmax[r];
        v = fmaxf(v, __shfl_xor(v, 1));
        v = fmaxf(v, __shfl_xor(v, 2));
        v = fmaxf(v, __shfl_xor(v, 4));
        v = fmaxf(v, __shfl_xor(v, 8));
        const float mnew = fmaxf(mrun[m][r], v);
        const float sc = __expf(mrun[m][r] - mnew);
        mrun[m][r] = mnew;
#pragma unroll
        for (int nd = 0; nd < 8; ++nd) acco[m][nd][r] *= sc;
        float rs = 0.f;
#pragma unroll
        for (int n = 0; n < 4; ++n) {
          float p = __expf(accs[m][n][r] - mnew);
          accs[m][n][r] = p;
          rs += p;
        }
        rs += __shfl_xor(rs, 1);
        rs += __shfl_xor(rs, 2);
        rs += __shfl_xor(rs, 4);
        rs += __shfl_xor(rs, 8);
        lrun[m][r] = lrun[m][r] * sc + rs;
        const int ql = wid * 32 + m * 16 + fg * 4 + r;
#pragma unroll
        for (int n = 0; n < 4; ++n) {
          const int cbyte = (n * 16 + fr) * 2;
          *(bf16*)((char*)Pl + ql * 128 + (cbyte ^ ((ql & 7) << 4))) = (bf16)accs[m][n][r];
        }
      }
    }

    // O += P V
#pragma unroll
    for (int kk = 0; kk < 2; ++kk) {
      bf16x8 pa[2];
#pragma unroll
      for (int m = 0; m < 2; ++m) {
        const int r = wid * 32 + m * 16 + fr;
        const int cb = (kk * 64 + fg * 16) ^ ((r & 7) << 4);
        pa[m] = *(const bf16x8*)((const char*)Pl + r * 128 + cb);
      }
#pragma unroll
      for (int nd = 0; nd < 8; ++nd) {
        const int r = nd * 16 + fr;
        const int cb = (kk * 64 + fg * 16) ^ ((r & 7) << 4);
        bf16x8 bv = *(const bf16x8*)((const char*)Vl + r * 128 + cb);
#pragma unroll
        for (int m = 0; m < 2; ++m) acco[m][nd] = mfma16(pa[m], bv, acco[m][nd]);
      }
    }
  }

  // epilogue
#pragma unroll
  for (int m = 0; m < 2; ++m) {
#pragma unroll
    for (int r = 0; r < 4; ++r) {
      const float inv = 1.f / lrun[m][r];
      const int qrow = q0 + wid * 32 + m * 16 + fg * 4 + r;
      bf16* orow = O + (((size_t)(b * SEQ + qrow) * NH + h) << 7);
#pragma unroll
      for (int nd = 0; nd < 8; ++nd) orow[nd * 16 + fr] = (bf16)(acco[m][nd][r] * inv);
    }
  }
}

extern "C" void kernel_launch(void* const* d_in, const int* in_sizes, int n_in,
                              void* d_out, int out_size, void* d_ws, size_t ws_size,
                              hipStream_t stream) {
  const float* states = (const float*)d_in[0];
  const float* maskp  = (const float*)d_in[1];
  const float* hscale = (const float*)d_in[2];
  const float* qw = (const float*)d_in[3];
  const float* qb = (const float*)d_in[4];
  const float* kw = (const float*)d_in[5];
  const float* kb = (const float*)d_in[6];
  const float* vw = (const float*)d_in[7];
  const float* vb = (const float*)d_in[8];
  const float* ow = (const float*)d_in[9];
  const float* ob = (const float*)d_in[10];

  char* ws = (char*)d_ws;
  const size_t SZ_ACT = (size_t)MTOT * DM * 2;  // 16 MiB
  const size_t SZ_W   = (size_t)DM * DM * 2;    // 8 MiB
  bf16* sb    = (bf16*)(ws);                    // states bf16; later reused as O buffer
  bf16* qbuf  = (bf16*)(ws + SZ_ACT);
  bf16* kbuf  = (bf16*)(ws + 2 * SZ_ACT);
  bf16* vtbuf = (bf16*)(ws + 3 * SZ_ACT);
  bf16* wqb   = (bf16*)(ws + 4 * SZ_ACT);
  bf16* wkb   = (bf16*)(ws + 4 * SZ_ACT + SZ_W);
  bf16* wvb   = (bf16*)(ws + 4 * SZ_ACT + 2 * SZ_W);
  bf16* wob   = (bf16*)(ws + 4 * SZ_ACT + 3 * SZ_W);
  // fp16 mask reuses wqb+wkb region (dead after QKV GEMMs): 16.8 MB
  f16* maskh  = (f16*)(ws + 4 * SZ_ACT);

  const int nAct4 = MTOT * DM / 4;
  const int nW4   = DM * DM / 4;
  const int nM4   = NB * SEQ * SEQ / 4;
  cast_kernel<<<(nAct4 + 255) / 256, 256, 0, stream>>>(states, sb, nAct4);
  cast_kernel<<<(nW4 + 255) / 256, 256, 0, stream>>>(qw, wqb, nW4);
  cast_kernel<<<(nW4 + 255) / 256, 256, 0, stream>>>(kw, wkb, nW4);
  cast_kernel<<<(nW4 + 255) / 256, 256, 0, stream>>>(vw, wvb, nW4);
  cast_kernel<<<(nW4 + 255) / 256, 256, 0, stream>>>(ow, wob, nW4);

  dim3 blk(256);
  dim3 gg(DM / 128, MTOT / 128, 1);
  gemm_bt<0><<<gg, blk, 0, stream>>>(sb, wqb, qb, qbuf);
  gemm_bt<0><<<gg, blk, 0, stream>>>(sb, wkb, kb, kbuf);
  gemm_bt<1><<<gg, blk, 0, stream>>>(sb, wvb, vb, vtbuf);

  // mask cast AFTER QKV GEMMs (overwrites wq/wk weight buffers)
  cast_half_kernel<<<(nM4 + 255) / 256, 256, 0, stream>>>(maskp, maskh, nM4);

  dim3 ga(SEQ / 128, NH, NB);
  attn_kernel<<<ga, blk, 0, stream>>>(qbuf, kbuf, vtbuf, maskh, hscale, sb);

  gemm_bt<2><<<gg, blk, 0, stream>>>(sb, wob, ob, d_out);
}

// Round 4
// 355.663 us; speedup vs baseline: 1.4392x; 1.0370x over previous
//
#include <hip/hip_runtime.h>
#include <hip/hip_bf16.h>
#include <stdint.h>

#define DM   2048
#define SEQ  2048
#define NB   2
#define NH   16
#define DK   128
#define MTOT (NB * SEQ) // 4096
#define NT   (SEQ / 64) // 32 k-tiles

typedef __bf16 bf16;
typedef _Float16 f16;
typedef __bf16 bf16x8 __attribute__((ext_vector_type(8)));
typedef __bf16 bf16x4v __attribute__((ext_vector_type(4)));
typedef _Float16 f16x4 __attribute__((ext_vector_type(4)));
typedef float f32x4 __attribute__((ext_vector_type(4)));

__device__ __forceinline__ void gload_lds16(const void* g, void* l) {
  __builtin_amdgcn_global_load_lds((__attribute__((address_space(1))) void*)(g),
                                   (__attribute__((address_space(3))) void*)(l),
                                   16, 0, 0);
}

__device__ __forceinline__ f32x4 mfma16(bf16x8 a, bf16x8 b, f32x4 c) {
  return __builtin_amdgcn_mfma_f32_16x16x32_bf16(a, b, c, 0, 0, 0);
}

// ---------------- fp32 -> bf16 cast ----------------
__global__ void cast_kernel(const float* __restrict__ in, bf16* __restrict__ out, int n4) {
  int i = blockIdx.x * blockDim.x + threadIdx.x;
  if (i < n4) {
    float4 v = reinterpret_cast<const float4*>(in)[i];
    bf16x4v o;
    o[0] = (bf16)v.x; o[1] = (bf16)v.y; o[2] = (bf16)v.z; o[3] = (bf16)v.w;
    *reinterpret_cast<bf16x4v*>(out + (size_t)i * 4) = o;
  }
}

// ---------------- fp32 -> fp16 cast (bias mask) ----------------
__global__ void cast_half_kernel(const float* __restrict__ in, f16* __restrict__ out, int n4) {
  int i = blockIdx.x * blockDim.x + threadIdx.x;
  if (i < n4) {
    float4 v = reinterpret_cast<const float4*>(in)[i];
    f16x4 o;
    o[0] = (f16)v.x; o[1] = (f16)v.y; o[2] = (f16)v.z; o[3] = (f16)v.w;
    *reinterpret_cast<f16x4*>(out + (size_t)i * 4) = o;
  }
}

// ---------------- GEMM: C[M,N] = A[M,K] * W[N,K]^T + bias ----------------
template <int MODE>
__global__ __launch_bounds__(256, 2) void gemm_bt(
    const bf16* __restrict__ A, const bf16* __restrict__ W,
    const float* __restrict__ bias, void* __restrict__ out) {
  __shared__ bf16 lA[128 * 64];
  __shared__ bf16 lB[128 * 64];

  const int tid = threadIdx.x;
  const int lane = tid & 63;
  const int wid = tid >> 6;
  const int wr = wid >> 1, wc = wid & 1;
  const int row0 = blockIdx.y * 128;
  const int col0 = blockIdx.x * 128;

  const int srow = lane >> 3;
  const int scol = ((lane & 7) ^ srow) * 8;

  const int fr = lane & 15;
  const int fg = lane >> 4;

  f32x4 acc[4][4];
#pragma unroll
  for (int m = 0; m < 4; ++m)
#pragma unroll
    for (int n = 0; n < 4; ++n) { f32x4 z = {0.f, 0.f, 0.f, 0.f}; acc[m][n] = z; }

  for (int kt = 0; kt < DM / 64; ++kt) {
    const int k0 = kt * 64;
    __syncthreads();
#pragma unroll
    for (int i = 0; i < 4; ++i) {
      const int chunk = wid * 4 + i;
      const int r = chunk * 8 + srow;
      gload_lds16(A + (size_t)(row0 + r) * DM + k0 + scol, lA + chunk * 512);
      gload_lds16(W + (size_t)(col0 + r) * DM + k0 + scol, lB + chunk * 512);
    }
    __syncthreads();
#pragma unroll
    for (int kk = 0; kk < 2; ++kk) {
      bf16x8 af[4], bw[4];
#pragma unroll
      for (int m = 0; m < 4; ++m) {
        const int r = wr * 64 + m * 16 + fr;
        const int cb = (kk * 64 + fg * 16) ^ ((r & 7) << 4);
        af[m] = *(const bf16x8*)((const char*)lA + r * 128 + cb);
      }
#pragma unroll
      for (int n = 0; n < 4; ++n) {
        const int r = wc * 64 + n * 16 + fr;
        const int cb = (kk * 64 + fg * 16) ^ ((r & 7) << 4);
        bw[n] = *(const bf16x8*)((const char*)lB + r * 128 + cb);
      }
#pragma unroll
      for (int m = 0; m < 4; ++m)
#pragma unroll
        for (int n = 0; n < 4; ++n) acc[m][n] = mfma16(af[m], bw[n], acc[m][n]);
    }
  }

#pragma unroll
  for (int m = 0; m < 4; ++m) {
#pragma unroll
    for (int n = 0; n < 4; ++n) {
      const int col = col0 + wc * 64 + n * 16 + fr;
      const float bs = bias[col];
      const int rbase = row0 + wr * 64 + m * 16 + fg * 4;
      if (MODE == 0) {
        bf16* o = (bf16*)out;
        const int h = col >> 7, d = col & 127;
#pragma unroll
        for (int r = 0; r < 4; ++r) {
          const int row = rbase + r;
          const int b = row >> 11, s = row & 2047;
          o[(((size_t)(b * NH + h) * SEQ + s) << 7) + d] = (bf16)(acc[m][n][r] + bs);
        }
      } else if (MODE == 1) {
        bf16* o = (bf16*)out;
        const int h = col >> 7, d = col & 127;
        const int b = rbase >> 11, s = rbase & 2047;
        bf16x4v pk;
#pragma unroll
        for (int r = 0; r < 4; ++r) pk[r] = (bf16)(acc[m][n][r] + bs);
        *reinterpret_cast<bf16x4v*>(o + ((size_t)((b * NH + h) * DK + d) * SEQ + s)) = pk;
      } else {
        float* o = (float*)out;
#pragma unroll
        for (int r = 0; r < 4; ++r) {
          const int row = rbase + r;
          o[(size_t)row * DM + col] = acc[m][n][r] + bs;
        }
      }
    }
  }
}

// ---------------- flash attention, pipelined (K dbuf, V early-stage, mask reg-prefetch) ----------------
// 1-D grid of 512 blocks; decoded so the 16 heads sharing a mask panel land on one XCD.
__global__ __launch_bounds__(256, 2) void attn_kernel(
    const bf16* __restrict__ Q,   // [B,H,S,DK]
    const bf16* __restrict__ K,   // [B,H,S,DK]
    const bf16* __restrict__ Vt,  // [B,H,DK,S]
    const f16* __restrict__ maskh,    // [B,S,S] fp16
    const float* __restrict__ hscale, // [NH]
    bf16* __restrict__ O) {           // [B,S,H,DK]
  __shared__ bf16 Kl[2][64 * 128];  // 32 KB double-buffered
  __shared__ bf16 Vl[128 * 64];     // 16 KB
  __shared__ bf16 Pl[128 * 64];     // 16 KB

  const int tid = threadIdx.x;
  const int lane = tid & 63;
  const int wid = tid >> 6;

  // block remap: bid -> (b, qtile, h) with the 16 heads of one (b,qtile) on one XCD
  const int bid = blockIdx.x;            // 0..511
  const int xcd = bid & 7;
  const int slot = bid >> 3;             // 0..63
  const int g = xcd + ((slot >> 4) << 3);// 0..31 group = b*16 + qtile
  const int h = slot & 15;
  const int qt = g & 15;
  const int b = g >> 4;
  const int q0 = qt * 128;

  const float hs = hscale[h];
  const float ksc = 0.08838834764831845f; // 1/sqrt(128)

  const size_t bh = (size_t)(b * NH + h);
  const bf16* Qb = Q + bh * SEQ * DK;
  const bf16* Kb = K + bh * SEQ * DK;
  const bf16* Vb = Vt + bh * (size_t)DK * SEQ;
  const f16*  Mb = maskh + (size_t)b * SEQ * SEQ;

  const int fr = lane & 15, fg = lane >> 4;

  // mask lane base: element (q0 + wid*32 + fg*4, fr); offsets (m*16+r)*SEQ + t*64 + n*16
  const f16* Mlane = Mb + (size_t)(q0 + wid * 32 + fg * 4) * SEQ + fr;

  // Q fragments in registers
  bf16x8 aq[2][4];
#pragma unroll
  for (int m = 0; m < 2; ++m) {
    const int qr = q0 + wid * 32 + m * 16 + fr;
#pragma unroll
    for (int kk = 0; kk < 4; ++kk)
      aq[m][kk] = *(const bf16x8*)(Qb + (size_t)qr * DK + kk * 32 + fg * 8);
  }

  f32x4 acco[2][8];
#pragma unroll
  for (int m = 0; m < 2; ++m)
#pragma unroll
    for (int nd = 0; nd < 8; ++nd) { f32x4 z = {0.f, 0.f, 0.f, 0.f}; acco[m][nd] = z; }
  float mrun[2][4], lrun[2][4];
#pragma unroll
  for (int m = 0; m < 2; ++m)
#pragma unroll
    for (int r = 0; r < 4; ++r) { mrun[m][r] = -3.0e38f; lrun[m][r] = 0.f; }

  const int k_r = lane >> 4;                 // K tile staging: 4-row chunks
  const int k_c = ((lane & 15) ^ 0) * 8;     // col base (row-dependent xor applied below)
  const int v_r = lane >> 3;                 // V tile staging: 8-row chunks
  const int v_c = ((lane & 7) ^ v_r) * 8;

  // ---- prologue: stage K(0) into Kl[0]
#pragma unroll
  for (int i = 0; i < 4; ++i) {
    const int chunk = wid * 4 + i;
    const int r = chunk * 4 + k_r;
    const int c = ((lane & 15) ^ (r & 7)) * 8;
    gload_lds16(Kb + (size_t)r * DK + c, Kl[0] + chunk * 512);
  }
  __syncthreads();

  for (int t = 0; t < NT; ++t) {
    const int kb0 = t * 64;
    bf16* Kc = Kl[t & 1];
    bf16* Kn = Kl[(t & 1) ^ 1];

    // 1. mask register prefetch for THIS tile (consumed after QK^T)
    f16 mcur[2][4][4];
#pragma unroll
    for (int m = 0; m < 2; ++m)
#pragma unroll
      for (int n = 0; n < 4; ++n)
#pragma unroll
        for (int r = 0; r < 4; ++r)
          mcur[m][n][r] = Mlane[(size_t)(m * 16 + r) * SEQ + kb0 + n * 16];

    // 2. stage V(t) (consumed at PV after B1)
#pragma unroll
    for (int i = 0; i < 4; ++i) {
      const int chunk = wid * 4 + i;
      const int r = chunk * 8 + v_r;
      gload_lds16(Vb + (size_t)r * SEQ + kb0 + v_c, Vl + chunk * 512);
    }
    // 3. stage K(t+1) into the other buffer
    if (t + 1 < NT) {
#pragma unroll
      for (int i = 0; i < 4; ++i) {
        const int chunk = wid * 4 + i;
        const int r = chunk * 4 + k_r;
        const int c = ((lane & 15) ^ (r & 7)) * 8;
        gload_lds16(Kb + (size_t)(kb0 + 64 + r) * DK + c, Kn + chunk * 512);
      }
    }

    // 4. QK^T from current K buffer
    f32x4 accs[2][4];
#pragma unroll
    for (int m = 0; m < 2; ++m)
#pragma unroll
      for (int n = 0; n < 4; ++n) { f32x4 z = {0.f, 0.f, 0.f, 0.f}; accs[m][n] = z; }
    __builtin_amdgcn_s_setprio(1);
#pragma unroll
    for (int kk = 0; kk < 4; ++kk) {
      bf16x8 bk[4];
#pragma unroll
      for (int n = 0; n < 4; ++n) {
        const int r = n * 16 + fr;
        const int cb = (kk * 64 + fg * 16) ^ ((r & 7) << 4);
        bk[n] = *(const bf16x8*)((const char*)Kc + r * 256 + cb);
      }
#pragma unroll
      for (int m = 0; m < 2; ++m)
#pragma unroll
        for (int n = 0; n < 4; ++n) accs[m][n] = mfma16(aq[m][kk], bk[n], accs[m][n]);
    }
    __builtin_amdgcn_s_setprio(0);

    // 5. softmax with register mask + defer-max
#pragma unroll
    for (int m = 0; m < 2; ++m) {
      float rmax[4] = {-3.0e38f, -3.0e38f, -3.0e38f, -3.0e38f};
#pragma unroll
      for (int n = 0; n < 4; ++n)
#pragma unroll
        for (int r = 0; r < 4; ++r) {
          float v = accs[m][n][r] * ksc + (float)mcur[m][n][r] * hs;
          accs[m][n][r] = v;
          rmax[r] = fmaxf(rmax[r], v);
        }
      float vr[4];
#pragma unroll
      for (int r = 0; r < 4; ++r) {
        float v = rmax[r];
        v = fmaxf(v, __shfl_xor(v, 1));
        v = fmaxf(v, __shfl_xor(v, 2));
        v = fmaxf(v, __shfl_xor(v, 4));
        v = fmaxf(v, __shfl_xor(v, 8));
        vr[r] = v;
      }
      float gmax = -3.0e38f;
#pragma unroll
      for (int r = 0; r < 4; ++r) gmax = fmaxf(gmax, vr[r] - mrun[m][r]);
      if (__any(gmax > 8.0f)) {
#pragma unroll
        for (int r = 0; r < 4; ++r) {
          const float mnew = fmaxf(mrun[m][r], vr[r]);
          const float sc = __expf(mrun[m][r] - mnew);
          mrun[m][r] = mnew;
          lrun[m][r] *= sc;
#pragma unroll
          for (int nd = 0; nd < 8; ++nd) acco[m][nd][r] *= sc;
        }
      }
#pragma unroll
      for (int r = 0; r < 4; ++r) {
        float rs = 0.f;
#pragma unroll
        for (int n = 0; n < 4; ++n) {
          float p = __expf(accs[m][n][r] - mrun[m][r]);
          accs[m][n][r] = p;
          rs += p;
        }
        rs += __shfl_xor(rs, 1);
        rs += __shfl_xor(rs, 2);
        rs += __shfl_xor(rs, 4);
        rs += __shfl_xor(rs, 8);
        lrun[m][r] += rs;
        const int ql = wid * 32 + m * 16 + fg * 4 + r;
#pragma unroll
        for (int n = 0; n < 4; ++n) {
          const int cbyte = (n * 16 + fr) * 2;
          *(bf16*)((char*)Pl + ql * 128 + (cbyte ^ ((ql & 7) << 4))) = (bf16)accs[m][n][r];
        }
      }
    }

    // B1: V(t) + K(t+1) staged (gload_lds are our only outstanding VMEM writes to LDS)
    asm volatile("s_waitcnt vmcnt(0)" ::: "memory");
    __builtin_amdgcn_sched_barrier(0);
    __builtin_amdgcn_s_barrier();

    // 6. O += P V
    __builtin_amdgcn_s_setprio(1);
#pragma unroll
    for (int kk = 0; kk < 2; ++kk) {
      bf16x8 pa[2];
#pragma unroll
      for (int m = 0; m < 2; ++m) {
        const int r = wid * 32 + m * 16 + fr;
        const int cb = (kk * 64 + fg * 16) ^ ((r & 7) << 4);
        pa[m] = *(const bf16x8*)((const char*)Pl + r * 128 + cb);
      }
#pragma unroll
      for (int nd = 0; nd < 8; ++nd) {
        const int r = nd * 16 + fr;
        const int cb = (kk * 64 + fg * 16) ^ ((r & 7) << 4);
        bf16x8 bv = *(const bf16x8*)((const char*)Vl + r * 128 + cb);
#pragma unroll
        for (int m = 0; m < 2; ++m) acco[m][nd] = mfma16(pa[m], bv, acco[m][nd]);
      }
    }
    __builtin_amdgcn_s_setprio(0);

    // B2: all waves done reading Vl before next tile restages it
    asm volatile("s_waitcnt lgkmcnt(0)" ::: "memory");
    __builtin_amdgcn_sched_barrier(0);
    __builtin_amdgcn_s_barrier();
  }

  // epilogue
#pragma unroll
  for (int m = 0; m < 2; ++m) {
#pragma unroll
    for (int r = 0; r < 4; ++r) {
      const float inv = 1.f / lrun[m][r];
      const int qrow = q0 + wid * 32 + m * 16 + fg * 4 + r;
      bf16* orow = O + (((size_t)(b * SEQ + qrow) * NH + h) << 7);
#pragma unroll
      for (int nd = 0; nd < 8; ++nd) orow[nd * 16 + fr] = (bf16)(acco[m][nd][r] * inv);
    }
  }
}

extern "C" void kernel_launch(void* const* d_in, const int* in_sizes, int n_in,
                              void* d_out, int out_size, void* d_ws, size_t ws_size,
                              hipStream_t stream) {
  const float* states = (const float*)d_in[0];
  const float* maskp  = (const float*)d_in[1];
  const float* hscale = (const float*)d_in[2];
  const float* qw = (const float*)d_in[3];
  const float* qb = (const float*)d_in[4];
  const float* kw = (const float*)d_in[5];
  const float* kb = (const float*)d_in[6];
  const float* vw = (const float*)d_in[7];
  const float* vb = (const float*)d_in[8];
  const float* ow = (const float*)d_in[9];
  const float* ob = (const float*)d_in[10];

  char* ws = (char*)d_ws;
  const size_t SZ_ACT = (size_t)MTOT * DM * 2;  // 16 MiB
  const size_t SZ_W   = (size_t)DM * DM * 2;    // 8 MiB
  bf16* sb    = (bf16*)(ws);                    // states bf16; later reused as O buffer
  bf16* qbuf  = (bf16*)(ws + SZ_ACT);
  bf16* kbuf  = (bf16*)(ws + 2 * SZ_ACT);
  bf16* vtbuf = (bf16*)(ws + 3 * SZ_ACT);
  bf16* wqb   = (bf16*)(ws + 4 * SZ_ACT);
  bf16* wkb   = (bf16*)(ws + 4 * SZ_ACT + SZ_W);
  bf16* wvb   = (bf16*)(ws + 4 * SZ_ACT + 2 * SZ_W);
  bf16* wob   = (bf16*)(ws + 4 * SZ_ACT + 3 * SZ_W);
  f16* maskh  = (f16*)(ws + 4 * SZ_ACT);        // reuses wq/wk region (dead after QKV GEMMs)

  const int nAct4 = MTOT * DM / 4;
  const int nW4   = DM * DM / 4;
  const int nM4   = NB * SEQ * SEQ / 4;
  cast_kernel<<<(nAct4 + 255) / 256, 256, 0, stream>>>(states, sb, nAct4);
  cast_kernel<<<(nW4 + 255) / 256, 256, 0, stream>>>(qw, wqb, nW4);
  cast_kernel<<<(nW4 + 255) / 256, 256, 0, stream>>>(kw, wkb, nW4);
  cast_kernel<<<(nW4 + 255) / 256, 256, 0, stream>>>(vw, wvb, nW4);
  cast_kernel<<<(nW4 + 255) / 256, 256, 0, stream>>>(ow, wob, nW4);

  dim3 blk(256);
  dim3 gg(DM / 128, MTOT / 128, 1);
  gemm_bt<0><<<gg, blk, 0, stream>>>(sb, wqb, qb, qbuf);
  gemm_bt<0><<<gg, blk, 0, stream>>>(sb, wkb, kb, kbuf);
  gemm_bt<1><<<gg, blk, 0, stream>>>(sb, wvb, vb, vtbuf);

  cast_half_kernel<<<(nM4 + 255) / 256, 256, 0, stream>>>(maskp, maskh, nM4);

  attn_kernel<<<dim3(NB * NH * (SEQ / 128)), blk, 0, stream>>>(qbuf, kbuf, vtbuf, maskh, hscale, sb);

  gemm_bt<2><<<gg, blk, 0, stream>>>(sb, wob, ob, d_out);
}

// Round 5
// 309.907 us; speedup vs baseline: 1.6516x; 1.1476x over previous
//
#include <hip/hip_runtime.h>
#include <hip/hip_bf16.h>
#include <stdint.h>

#define DM   2048
#define SEQ  2048
#define NB   2
#define NH   16
#define DK   128
#define MTOT (NB * SEQ) // 4096
#define NT   (SEQ / 64) // 32 k-tiles

typedef __bf16 bf16;
typedef _Float16 f16;
typedef __bf16 bf16x8 __attribute__((ext_vector_type(8)));
typedef __bf16 bf16x4v __attribute__((ext_vector_type(4)));
typedef _Float16 f16x4 __attribute__((ext_vector_type(4)));
typedef float f32x4 __attribute__((ext_vector_type(4)));
typedef float f32x16 __attribute__((ext_vector_type(16)));

__device__ __forceinline__ void gload_lds16(const void* g, void* l) {
  __builtin_amdgcn_global_load_lds((__attribute__((address_space(1))) void*)(g),
                                   (__attribute__((address_space(3))) void*)(l),
                                   16, 0, 0);
}

__device__ __forceinline__ f32x4 mfma16(bf16x8 a, bf16x8 b, f32x4 c) {
  return __builtin_amdgcn_mfma_f32_16x16x32_bf16(a, b, c, 0, 0, 0);
}
__device__ __forceinline__ f32x16 mfma32(bf16x8 a, bf16x8 b, f32x16 c) {
  return __builtin_amdgcn_mfma_f32_32x32x16_bf16(a, b, c, 0, 0, 0);
}
__device__ __forceinline__ uint32_t cvtpk(float lo, float hi) {
  uint32_t r;
  asm("v_cvt_pk_bf16_f32 %0, %1, %2" : "=v"(r) : "v"(lo), "v"(hi));
  return r;
}

// ---------------- fp32 -> bf16 cast ----------------
__global__ void cast_kernel(const float* __restrict__ in, bf16* __restrict__ out, int n4) {
  int i = blockIdx.x * blockDim.x + threadIdx.x;
  if (i < n4) {
    float4 v = reinterpret_cast<const float4*>(in)[i];
    bf16x4v o;
    o[0] = (bf16)v.x; o[1] = (bf16)v.y; o[2] = (bf16)v.z; o[3] = (bf16)v.w;
    *reinterpret_cast<bf16x4v*>(out + (size_t)i * 4) = o;
  }
}

// ---------------- fp32 -> fp16 cast (bias mask) ----------------
__global__ void cast_half_kernel(const float* __restrict__ in, f16* __restrict__ out, int n4) {
  int i = blockIdx.x * blockDim.x + threadIdx.x;
  if (i < n4) {
    float4 v = reinterpret_cast<const float4*>(in)[i];
    f16x4 o;
    o[0] = (f16)v.x; o[1] = (f16)v.y; o[2] = (f16)v.z; o[3] = (f16)v.w;
    *reinterpret_cast<f16x4*>(out + (size_t)i * 4) = o;
  }
}

// ---------------- GEMM: C[M,N] = A[M,K] * W[N,K]^T + bias ----------------
template <int MODE>
__global__ __launch_bounds__(256, 2) void gemm_bt(
    const bf16* __restrict__ A, const bf16* __restrict__ W,
    const float* __restrict__ bias, void* __restrict__ out) {
  __shared__ bf16 lA[128 * 64];
  __shared__ bf16 lB[128 * 64];

  const int tid = threadIdx.x;
  const int lane = tid & 63;
  const int wid = tid >> 6;
  const int wr = wid >> 1, wc = wid & 1;
  const int row0 = blockIdx.y * 128;
  const int col0 = blockIdx.x * 128;

  const int srow = lane >> 3;
  const int scol = ((lane & 7) ^ srow) * 8;

  const int fr = lane & 15;
  const int fg = lane >> 4;

  f32x4 acc[4][4];
#pragma unroll
  for (int m = 0; m < 4; ++m)
#pragma unroll
    for (int n = 0; n < 4; ++n) { f32x4 z = {0.f, 0.f, 0.f, 0.f}; acc[m][n] = z; }

  for (int kt = 0; kt < DM / 64; ++kt) {
    const int k0 = kt * 64;
    __syncthreads();
#pragma unroll
    for (int i = 0; i < 4; ++i) {
      const int chunk = wid * 4 + i;
      const int r = chunk * 8 + srow;
      gload_lds16(A + (size_t)(row0 + r) * DM + k0 + scol, lA + chunk * 512);
      gload_lds16(W + (size_t)(col0 + r) * DM + k0 + scol, lB + chunk * 512);
    }
    __syncthreads();
#pragma unroll
    for (int kk = 0; kk < 2; ++kk) {
      bf16x8 af[4], bw[4];
#pragma unroll
      for (int m = 0; m < 4; ++m) {
        const int r = wr * 64 + m * 16 + fr;
        const int cb = (kk * 64 + fg * 16) ^ ((r & 7) << 4);
        af[m] = *(const bf16x8*)((const char*)lA + r * 128 + cb);
      }
#pragma unroll
      for (int n = 0; n < 4; ++n) {
        const int r = wc * 64 + n * 16 + fr;
        const int cb = (kk * 64 + fg * 16) ^ ((r & 7) << 4);
        bw[n] = *(const bf16x8*)((const char*)lB + r * 128 + cb);
      }
#pragma unroll
      for (int m = 0; m < 4; ++m)
#pragma unroll
        for (int n = 0; n < 4; ++n) acc[m][n] = mfma16(af[m], bw[n], acc[m][n]);
    }
  }

#pragma unroll
  for (int m = 0; m < 4; ++m) {
#pragma unroll
    for (int n = 0; n < 4; ++n) {
      const int col = col0 + wc * 64 + n * 16 + fr;
      const float bs = bias[col];
      const int rbase = row0 + wr * 64 + m * 16 + fg * 4;
      if (MODE == 0) {
        bf16* o = (bf16*)out;
        const int h = col >> 7, d = col & 127;
#pragma unroll
        for (int r = 0; r < 4; ++r) {
          const int row = rbase + r;
          const int b = row >> 11, s = row & 2047;
          o[(((size_t)(b * NH + h) * SEQ + s) << 7) + d] = (bf16)(acc[m][n][r] + bs);
        }
      } else if (MODE == 1) {
        bf16* o = (bf16*)out;
        const int h = col >> 7, d = col & 127;
        const int b = rbase >> 11, s = rbase & 2047;
        bf16x4v pk;
#pragma unroll
        for (int r = 0; r < 4; ++r) pk[r] = (bf16)(acc[m][n][r] + bs);
        *reinterpret_cast<bf16x4v*>(o + ((size_t)((b * NH + h) * DK + d) * SEQ + s)) = pk;
      } else {
        float* o = (float*)out;
#pragma unroll
        for (int r = 0; r < 4; ++r) {
          const int row = rbase + r;
          o[(size_t)row * DM + col] = acc[m][n][r] + bs;
        }
      }
    }
  }
}

// ---------------- flash attention: swapped QK^T, in-register softmax ----------------
// block = 4 waves, each wave owns 32 q-rows (block covers 128). grid 512 blocks.
// S^T = mfma32(K, Q): lane owns q = lane&31; k spread over 16 regs x 2 subtiles
// (k_local = (r&3) + 8*(r>>2) + 4*(lane>>5)). Softmax is in-lane + one shfl_xor(32).
// P -> PV A-frag via v_cvt_pk_bf16_f32 + shfl_xor(32) (T12). One barrier per tile.
__global__ __launch_bounds__(256, 2) void attn_kernel(
    const bf16* __restrict__ Q,   // [B,H,S,DK]
    const bf16* __restrict__ K,   // [B,H,S,DK]
    const bf16* __restrict__ Vt,  // [B,H,DK,S]
    const f16* __restrict__ maskh,    // [B,S,S] fp16
    const float* __restrict__ hscale, // [NH]
    bf16* __restrict__ O) {           // [B,S,H,DK]
  __shared__ bf16 Kl[2][64 * 128];  // [k=64][d=128], rows 256B, swizzle ^((row&7)<<4)
  __shared__ bf16 Vl[2][128 * 64];  // [d=128][k=64], rows 128B, swizzle ^((row&7)<<4)

  const int tid = threadIdx.x;
  const int lane = tid & 63;
  const int wv = tid >> 6;
  const int l31 = lane & 31;
  const int hi = lane >> 5;
  const int ksw = (l31 & 7) << 4;  // read-side swizzle (rows 32-periodic -> row&7 == l31&7)

  // block remap: heads of one (b,qtile) share an XCD (mask panel L2 locality)
  const int bid = blockIdx.x;            // 0..511
  const int xcd = bid & 7;
  const int slot = bid >> 3;             // 0..63
  const int g = xcd + ((slot >> 4) << 3);// 0..31 = b*16 + qtile
  const int h = slot & 15;
  const int qt = g & 15;
  const int b = g >> 4;
  const int q0 = qt * 128;

  const float hs = hscale[h];
  const float ksc = 0.08838834764831845f; // 1/sqrt(128)

  const size_t bh = (size_t)(b * NH + h);
  const bf16* Qb = Q + bh * SEQ * DK;
  const bf16* Kb = K + bh * SEQ * DK;
  const bf16* Vb = Vt + bh * (size_t)DK * SEQ;
  const f16*  Mrow = maskh + (size_t)b * SEQ * SEQ + (size_t)(q0 + wv * 32 + l31) * SEQ;

  // Q fragments: lane holds Q[q0+wv*32+l31][s*16 + hi*8 .. +8] for s=0..7
  bf16x8 qreg[8];
  {
    const bf16* qrow = Qb + (size_t)(q0 + wv * 32 + l31) * DK + hi * 8;
#pragma unroll
    for (int s = 0; s < 8; ++s) qreg[s] = *(const bf16x8*)(qrow + s * 16);
  }

  f32x16 acco[4];
#pragma unroll
  for (int nd = 0; nd < 4; ++nd) acco[nd] = (f32x16)(0.0f);
  float m_ = -3.0e38f, l_ = 0.f;

  // staging lanes
  const int kst_r = lane >> 4;               // K: 4-row chunks of 256B rows
  const int vst_r = lane >> 3;               // V: 8-row chunks of 128B rows
  const int vst_c = ((lane & 7) ^ vst_r) * 8;

  // prologue: stage tile 0
#pragma unroll
  for (int i = 0; i < 4; ++i) {
    const int chunk = wv * 4 + i;
    {
      const int r = chunk * 4 + kst_r;
      const int c = ((lane & 15) ^ (r & 7)) * 8;
      gload_lds16(Kb + (size_t)r * DK + c, Kl[0] + chunk * 512);
    }
    {
      const int r = chunk * 8 + vst_r;
      gload_lds16(Vb + (size_t)r * SEQ + vst_c, Vl[0] + chunk * 512);
    }
  }
  __syncthreads();

  for (int t = 0; t < NT; ++t) {
    const int kb0 = t * 64;
    const int cur = t & 1, nxt = cur ^ 1;
    const bf16* Kc = Kl[cur];
    const bf16* Vc = Vl[cur];

    // stage tile t+1 (completion waited at end-of-tile barrier)
    if (t + 1 < NT) {
#pragma unroll
      for (int i = 0; i < 4; ++i) {
        const int chunk = wv * 4 + i;
        {
          const int r = chunk * 4 + kst_r;
          const int c = ((lane & 15) ^ (r & 7)) * 8;
          gload_lds16(Kb + (size_t)(kb0 + 64 + r) * DK + c, Kl[nxt] + chunk * 512);
        }
        {
          const int r = chunk * 8 + vst_r;
          gload_lds16(Vb + (size_t)r * SEQ + kb0 + 64 + vst_c, Vl[nxt] + chunk * 512);
        }
      }
    }

    // mask chunks: lane needs mask[q=l31-row][kb0 + st*32 + c*8 + hi*4 + 0..3]
    f16x4 mk[2][4];
#pragma unroll
    for (int st = 0; st < 2; ++st)
#pragma unroll
      for (int c = 0; c < 4; ++c)
        mk[st][c] = *(const f16x4*)(Mrow + kb0 + st * 32 + c * 8 + hi * 4);

    // QK^T: p[st] = K(sub st) . Q^T  -> D[k_local][q], col q = l31
    f32x16 p[2];
#pragma unroll
    for (int st = 0; st < 2; ++st) p[st] = (f32x16)(0.0f);
    __builtin_amdgcn_s_setprio(1);
#pragma unroll
    for (int s = 0; s < 8; ++s) {
      const int byteoff = (s * 32 + hi * 16) ^ ksw;
      bf16x8 k0 = *(const bf16x8*)((const char*)Kc + (size_t)l31 * 256 + byteoff);
      bf16x8 k1 = *(const bf16x8*)((const char*)Kc + (size_t)(32 + l31) * 256 + byteoff);
      p[0] = mfma32(k0, qreg[s], p[0]);
      p[1] = mfma32(k1, qreg[s], p[1]);
    }
    __builtin_amdgcn_s_setprio(0);

    // logits
    float lg[32];
#pragma unroll
    for (int st = 0; st < 2; ++st)
#pragma unroll
      for (int r = 0; r < 16; ++r)
        lg[st * 16 + r] = p[st][r] * ksc + (float)mk[st][r >> 2][r & 3] * hs;

    // row max: in-lane over 32 + one cross-half exchange
    float mx = lg[0];
#pragma unroll
    for (int i = 1; i < 32; ++i) mx = fmaxf(mx, lg[i]);
    mx = fmaxf(mx, __shfl_xor(mx, 32));

    if (__any(mx - m_ > 8.0f)) {       // defer-max (T13): rescale rarely
      const float mnew = fmaxf(m_, mx);
      const float sc = __expf(m_ - mnew);
      m_ = mnew;
      l_ *= sc;
#pragma unroll
      for (int r = 0; r < 16; ++r) {
        const float scr = __shfl(sc, (r & 3) + 8 * (r >> 2) + 4 * hi);
#pragma unroll
        for (int nd = 0; nd < 4; ++nd) acco[nd][r] *= scr;
      }
    }

    // exp + row sum
    float es = 0.f;
#pragma unroll
    for (int i = 0; i < 32; ++i) {
      const float e = __expf(lg[i] - m_);
      lg[i] = e;
      es += e;
    }
    es += __shfl_xor(es, 32);
    l_ += es;

    // pack P -> PV A-frags (4 k-steps of 16). Lane layout (derived & lane-checked):
    //  lo: {w0,w1, x0,x1}   hi: {x2,x3, w2,w3}   (x = partner's w via shfl_xor 32)
    bf16x8 pa[4];
#pragma unroll
    for (int ks = 0; ks < 4; ++ks) {
      const int st = ks >> 1, bo = (ks & 1) * 8 + (st << 4);
      const uint32_t w0 = cvtpk(lg[bo + 0], lg[bo + 1]);
      const uint32_t w1 = cvtpk(lg[bo + 2], lg[bo + 3]);
      const uint32_t w2 = cvtpk(lg[bo + 4], lg[bo + 5]);
      const uint32_t w3 = cvtpk(lg[bo + 6], lg[bo + 7]);
      const uint32_t x0 = __shfl_xor(w0, 32);
      const uint32_t x1 = __shfl_xor(w1, 32);
      const uint32_t x2 = __shfl_xor(w2, 32);
      const uint32_t x3 = __shfl_xor(w3, 32);
      union { uint32_t u[4]; bf16x8 v; } pk;
      pk.u[0] = hi ? x2 : w0;
      pk.u[1] = hi ? x3 : w1;
      pk.u[2] = hi ? w2 : x0;
      pk.u[3] = hi ? w3 : x1;
      pa[ks] = pk.v;
    }

    // PV: O[q][d] += P V ; B-frag from Vl rows d = nd*32 + l31
    __builtin_amdgcn_s_setprio(1);
#pragma unroll
    for (int nd = 0; nd < 4; ++nd) {
#pragma unroll
      for (int ks = 0; ks < 4; ++ks) {
        const int byteoff = (ks * 32 + hi * 16) ^ ksw;
        bf16x8 vf = *(const bf16x8*)((const char*)Vc + (size_t)(nd * 32 + l31) * 128 + byteoff);
        acco[nd] = mfma32(pa[ks], vf, acco[nd]);
      }
    }
    __builtin_amdgcn_s_setprio(0);

    // single end-of-tile barrier: staged t+1 landed, all waves done with cur bufs
    asm volatile("s_waitcnt vmcnt(0) lgkmcnt(0)" ::: "memory");
    __builtin_amdgcn_sched_barrier(0);
    __builtin_amdgcn_s_barrier();
  }

  // epilogue: normalize (per-q inv via lane broadcast) and store [B,S,H,DK]
  const float inv = 1.f / l_;
#pragma unroll
  for (int r = 0; r < 16; ++r) {
    const int qloc = (r & 3) + 8 * (r >> 2) + 4 * hi;
    const float ivr = __shfl(inv, qloc);
    const int q_abs = q0 + wv * 32 + qloc;
    bf16* orow = O + (((size_t)(b * SEQ + q_abs) * NH + h) << 7) + l31;
#pragma unroll
    for (int nd = 0; nd < 4; ++nd) orow[nd * 32] = (bf16)(acco[nd][r] * ivr);
  }
}

extern "C" void kernel_launch(void* const* d_in, const int* in_sizes, int n_in,
                              void* d_out, int out_size, void* d_ws, size_t ws_size,
                              hipStream_t stream) {
  const float* states = (const float*)d_in[0];
  const float* maskp  = (const float*)d_in[1];
  const float* hscale = (const float*)d_in[2];
  const float* qw = (const float*)d_in[3];
  const float* qb = (const float*)d_in[4];
  const float* kw = (const float*)d_in[5];
  const float* kb = (const float*)d_in[6];
  const float* vw = (const float*)d_in[7];
  const float* vb = (const float*)d_in[8];
  const float* ow = (const float*)d_in[9];
  const float* ob = (const float*)d_in[10];

  char* ws = (char*)d_ws;
  const size_t SZ_ACT = (size_t)MTOT * DM * 2;  // 16 MiB
  const size_t SZ_W   = (size_t)DM * DM * 2;    // 8 MiB
  bf16* sb    = (bf16*)(ws);                    // states bf16; later reused as O buffer
  bf16* qbuf  = (bf16*)(ws + SZ_ACT);
  bf16* kbuf  = (bf16*)(ws + 2 * SZ_ACT);
  bf16* vtbuf = (bf16*)(ws + 3 * SZ_ACT);
  bf16* wqb   = (bf16*)(ws + 4 * SZ_ACT);
  bf16* wkb   = (bf16*)(ws + 4 * SZ_ACT + SZ_W);
  bf16* wvb   = (bf16*)(ws + 4 * SZ_ACT + 2 * SZ_W);
  bf16* wob   = (bf16*)(ws + 4 * SZ_ACT + 3 * SZ_W);
  f16* maskh  = (f16*)(ws + 4 * SZ_ACT);        // reuses wq/wk region (dead after QKV GEMMs)

  const int nAct4 = MTOT * DM / 4;
  const int nW4   = DM * DM / 4;
  const int nM4   = NB * SEQ * SEQ / 4;
  cast_kernel<<<(nAct4 + 255) / 256, 256, 0, stream>>>(states, sb, nAct4);
  cast_kernel<<<(nW4 + 255) / 256, 256, 0, stream>>>(qw, wqb, nW4);
  cast_kernel<<<(nW4 + 255) / 256, 256, 0, stream>>>(kw, wkb, nW4);
  cast_kernel<<<(nW4 + 255) / 256, 256, 0, stream>>>(vw, wvb, nW4);
  cast_kernel<<<(nW4 + 255) / 256, 256, 0, stream>>>(ow, wob, nW4);

  dim3 blk(256);
  dim3 gg(DM / 128, MTOT / 128, 1);
  gemm_bt<0><<<gg, blk, 0, stream>>>(sb, wqb, qb, qbuf);
  gemm_bt<0><<<gg, blk, 0, stream>>>(sb, wkb, kb, kbuf);
  gemm_bt<1><<<gg, blk, 0, stream>>>(sb, wvb, vb, vtbuf);

  cast_half_kernel<<<(nM4 + 255) / 256, 256, 0, stream>>>(maskp, maskh, nM4);

  attn_kernel<<<dim3(NB * NH * (SEQ / 128)), blk, 0, stream>>>(qbuf, kbuf, vtbuf, maskh, hscale, sb);

  gemm_bt<2><<<gg, blk, 0, stream>>>(sb, wob, ob, d_out);
}